// Round 1
// baseline (57981.726 us; speedup 1.0000x reference)
//
#include <hip/hip_runtime.h>

#define NB 256
#define NT 512

#define Bv 512
#define Tv 256
#define XDv 128
#define Hv 512
#define DDv 16
#define Pv 32
#define INv 272   // 2*XD + DD
#define G3v 1536  // 3*H

// ---- workspace layout (float offsets) ----
#define OFF_VALP 1024
#define OFF_M    (OFF_VALP + 16384)
#define OFF_C    (OFF_M + 16384)
#define OFF_KEYP (OFF_C + 1024)
#define OFF_GAM  (OFF_KEYP + 16384)
#define OFF_HNEW (OFF_GAM + Bv*Hv)
#define OFF_HP   (OFF_HNEW + Bv*Hv)
#define OFF_XH   (OFF_HP + Bv*Hv)
#define OFF_GH   (OFF_XH + Bv*XDv)
#define OFF_PS   (OFF_GH + Bv*G3v)   // 16 jt-tiles * 512 b * 34 (32 score + ah + pad)

// ---- output layout (flat, return order) ----
#define OUT_HS  0
#define OUT_HN  (Bv*Tv*Hv)
#define OUT_XCS (OUT_HN + Bv*Hv)
#define OUT_ZCS (OUT_XCS + Bv*Tv*XDv)

struct LDSB { float sc[2][Pv]; float h1s[2][Hv]; float red[2][16]; float alpha[2]; };
struct LDSC { float As[32][68]; float Bs[96][69]; float hpS[4][512]; float xcS[4][128]; };
struct LDSD { union { float inpS[32][276]; float timesS[32][128]; } u; float gxS[32][97]; float hfS[32][33]; };
union  LDSU { LDSB b; LDSC c; LDSD d; };

__device__ __forceinline__ float sig_f(float x) { return 1.f / (1.f + __expf(-x)); }
__device__ __forceinline__ float tanh_f(float x) {
  x = fminf(fmaxf(x, -15.f), 15.f);
  float e = __expf(2.f * x);
  return (e - 1.f) / (e + 1.f);
}

__device__ __forceinline__ void gridbar(unsigned int* bar, unsigned int& lgen) {
  __syncthreads();
  if (threadIdx.x == 0) {
    __threadfence();  // make this block's stores device-visible
    unsigned int target = ++lgen;
    unsigned int prev = __hip_atomic_fetch_add(&bar[0], 1u, __ATOMIC_ACQ_REL, __HIP_MEMORY_SCOPE_AGENT);
    if (prev == (unsigned)(NB - 1)) {
      __hip_atomic_store(&bar[0], 0u, __ATOMIC_RELAXED, __HIP_MEMORY_SCOPE_AGENT);
      __hip_atomic_store(&bar[1], target, __ATOMIC_RELEASE, __HIP_MEMORY_SCOPE_AGENT);
    } else {
      while (__hip_atomic_load(&bar[1], __ATOMIC_ACQUIRE, __HIP_MEMORY_SCOPE_AGENT) < target)
        __builtin_amdgcn_s_sleep(8);
    }
    __threadfence();
  }
  __syncthreads();
}

__global__ __launch_bounds__(NT, 1)
void rits_main(const float* __restrict__ values, const int* __restrict__ lens,
               const float* __restrict__ statc, const float* __restrict__ times,
               const float* __restrict__ masks, const float* __restrict__ prototype,
               const int* __restrict__ protoflag,
               const float* __restrict__ Wd, const float* __restrict__ bd,
               const float* __restrict__ Wh, const float* __restrict__ bh,
               const float* __restrict__ Wf, const float* __restrict__ bf,
               const float* __restrict__ Wq, const float* __restrict__ bq,
               const float* __restrict__ Wk, const float* __restrict__ bk,
               const float* __restrict__ Wv, const float* __restrict__ bv,
               const float* __restrict__ Wg, const float* __restrict__ bg,
               const float* __restrict__ Wih, const float* __restrict__ Whh,
               const float* __restrict__ bih, const float* __restrict__ bhh,
               float* __restrict__ out, float* __restrict__ ws)
{
  const int bid = blockIdx.x, tid = threadIdx.x;
  const int gtid = bid * NT + tid;
  unsigned int* bar = (unsigned int*)ws;
  unsigned int lgen = 0;

  float* w_valp = ws + OFF_VALP;
  float* w_M    = ws + OFF_M;
  float* w_c    = ws + OFF_C;
  float* w_keyp = ws + OFF_KEYP;
  float* w_gam  = ws + OFF_GAM;
  float* w_hnew = ws + OFF_HNEW;
  float* w_hp   = ws + OFF_HP;
  float* w_xh   = ws + OFF_XH;
  float* w_gh   = ws + OFF_GH;
  float* w_ps   = ws + OFF_PS;

  __shared__ LDSU L;
  const bool proto = (*protoflag) != 0;
  const float scale = 0.17677669529663687f;  // 1/sqrt(32)

  // ================= INIT 1: zero state, keyp/valp, gamma(0) =================
  for (int i = gtid; i < Bv*Hv; i += NB*NT) w_hnew[i] = 0.f;
  for (int i = gtid; i < Bv*XDv; i += NB*NT) w_xh[i] = 0.f;
  for (int i = gtid; i < 16*Bv*34; i += NB*NT) w_ps[i] = 0.f;
  for (int o = gtid; o < 2*Pv*Hv; o += NB*NT) {
    int which = o >> 14; int rem = o & 16383;
    int p = rem >> 9, j = rem & 511;
    const float* W = which ? Wv : Wk;
    const float* bb = which ? bv : bk;
    const float* pr = prototype + p*Hv;
    const float* wr = W + j*Hv;
    float s = bb[j];
    #pragma unroll 4
    for (int k = 0; k < Hv; ++k) s += pr[k]*wr[k];
    (which ? w_valp : w_keyp)[p*Hv + j] = s;
  }
  for (int o = gtid; o < Bv*Hv; o += NB*NT) {
    int b = o >> 9, j = o & 511;
    const float* tr = times + (b*Tv + 0)*XDv;
    const float* wr = Wd + j*XDv;
    float s = bd[j];
    #pragma unroll 4
    for (int x = 0; x < XDv; ++x) s += tr[x]*wr[x];
    w_gam[o] = __expf(-fmaxf(s, 0.f));
  }
  gridbar(bar, lgen);

  // ================= INIT 2: M = keyp @ Wq, c = bq @ keyp^T =================
  for (int o = gtid; o < Pv*Hv; o += NB*NT) {
    int p = o >> 9, k = o & 511;
    const float* kp = w_keyp + p*Hv;
    float s = 0.f;
    #pragma unroll 4
    for (int j = 0; j < Hv; ++j) s += kp[j]*Wq[j*Hv + k];
    w_M[o] = s;
  }
  if (gtid < Pv) {
    const float* kp = w_keyp + gtid*Hv;
    float s = 0.f;
    for (int j = 0; j < Hv; ++j) s += bq[j]*kp[j];
    w_c[gtid] = s;
  }
  gridbar(bar, lgen);

  // ================= MAIN TIME LOOP =================
  for (int t = 0; t < Tv; ++t) {
    // ---------- Phase B: proto (score-reduce, softmax, h1, blend) + *gamma ----------
    {
      const int half = tid >> 8, lane = tid & 255;
      const int b = bid*2 + half;
      if (proto) {
        if (lane < 33) {
          float s = 0.f;
          for (int jt = 0; jt < 16; ++jt) s += w_ps[(jt*Bv + b)*34 + lane];
          if (lane < 32) L.b.sc[half][lane] = (s + w_c[lane]) * scale;
          else L.b.red[half][0] = s;  // ah = dot(h, Wg[0:H]) partial-sum
        }
        __syncthreads();
        if (lane < 32) {
          float v = L.b.sc[half][lane];
          float mx = v;
          for (int d = 16; d >= 1; d >>= 1) mx = fmaxf(mx, __shfl_xor(mx, d, 32));
          float e = __expf(v - mx);
          float sm = e;
          for (int d = 16; d >= 1; d >>= 1) sm += __shfl_xor(sm, d, 32);
          L.b.sc[half][lane] = e / sm;
        }
        __syncthreads();
        {
          int j0 = lane*2;
          float a0 = 0.f, a1 = 0.f;
          #pragma unroll 8
          for (int p = 0; p < Pv; ++p) {
            float ap = L.b.sc[half][p];
            float2 vv = *(const float2*)(w_valp + p*Hv + j0);
            a0 += ap*vv.x; a1 += ap*vv.y;
          }
          L.b.h1s[half][j0] = a0; L.b.h1s[half][j0+1] = a1;
          float2 wg = *(const float2*)(Wg + Hv + j0);
          float pa = a0*wg.x + a1*wg.y;
          for (int d = 32; d >= 1; d >>= 1) pa += __shfl_xor(pa, d, 64);
          if ((tid & 63) == 0) L.b.red[half][1 + (lane >> 6)] = pa;
        }
        __syncthreads();
        if (lane == 0) {
          float a1s = L.b.red[half][1] + L.b.red[half][2] + L.b.red[half][3] + L.b.red[half][4];
          L.b.alpha[half] = sig_f(L.b.red[half][0] + a1s + bg[0]);
        }
        __syncthreads();
        {
          float al = L.b.alpha[half];
          int j0 = lane*2;
          float2 hv = *(const float2*)(w_hnew + b*Hv + j0);
          float2 gv = *(const float2*)(w_gam + b*Hv + j0);
          float o0 = (al*hv.x + (1.f-al)*L.b.h1s[half][j0  ]) * gv.x;
          float o1 = (al*hv.y + (1.f-al)*L.b.h1s[half][j0+1]) * gv.y;
          *(float2*)(w_hp + b*Hv + j0) = make_float2(o0, o1);
        }
      } else {
        int j0 = lane*2;
        float2 hv = *(const float2*)(w_hnew + b*Hv + j0);
        float2 gv = *(const float2*)(w_gam + b*Hv + j0);
        *(float2*)(w_hp + b*Hv + j0) = make_float2(hv.x*gv.x, hv.y*gv.y);
      }
    }
    gridbar(bar, lgen);

    // ---------- Phase C: gh = h'@Whh^T (tiled) ; blocks<128 also run x-chain ----------
    {
      const int btc = bid >> 4, ntc = bid & 15;
      const int r0 = btc*32, c0 = ntc*96;
      const int mi = tid >> 5, nj = tid & 31;
      const int i0 = mi*2, j0 = nj*3;
      float acc[2][3] = {{0.f,0.f,0.f},{0.f,0.f,0.f}};
      for (int kc = 0; kc < Hv; kc += 64) {
        {
          int i = tid >> 4, k4 = (tid & 15)*4;
          *(float4*)&L.c.As[i][k4] = *(const float4*)(w_hp + (r0+i)*Hv + kc + k4);
        }
        #pragma unroll
        for (int rep = 0; rep < 3; ++rep) {
          int j = rep*32 + (tid >> 4);
          int k4 = (tid & 15)*4;
          float4 v = *(const float4*)(Whh + (c0+j)*Hv + kc + k4);
          L.c.Bs[j][k4] = v.x; L.c.Bs[j][k4+1] = v.y; L.c.Bs[j][k4+2] = v.z; L.c.Bs[j][k4+3] = v.w;
        }
        __syncthreads();
        #pragma unroll 4
        for (int k = 0; k < 64; ++k) {
          float a0 = L.c.As[i0][k], a1 = L.c.As[i0+1][k];
          float b0 = L.c.Bs[j0][k], b1 = L.c.Bs[j0+1][k], b2 = L.c.Bs[j0+2][k];
          acc[0][0] += a0*b0; acc[0][1] += a0*b1; acc[0][2] += a0*b2;
          acc[1][0] += a1*b0; acc[1][1] += a1*b1; acc[1][2] += a1*b2;
        }
        __syncthreads();
      }
      #pragma unroll
      for (int r = 0; r < 2; ++r)
        #pragma unroll
        for (int c = 0; c < 3; ++c)
          w_gh[(r0+i0+r)*G3v + c0 + j0 + c] = acc[r][c] + bhh[c0+j0+c];

      if (bid < 128) {
        const int r0x = bid*4;
        const int rr = tid >> 7, ii = tid & 127;
        {
          int r = tid >> 7, k4 = (tid & 127)*4;
          *(float4*)&L.c.hpS[r][k4] = *(const float4*)(w_hp + (r0x+r)*Hv + k4);
        }
        __syncthreads();
        const int b = r0x + rr;
        const bool v = (t < lens[b]);
        float xhv;
        if (v) {
          float s = bh[ii];
          const float* wr = Wh + ii*Hv;
          #pragma unroll 4
          for (int k = 0; k < Hv; ++k) s += L.c.hpS[rr][k]*wr[k];
          w_xh[b*XDv + ii] = s;
          xhv = s;
        } else xhv = w_xh[b*XDv + ii];
        const int xoff = (b*Tv + t)*XDv + ii;
        float xv = values[xoff], mv = masks[xoff];
        float xc = mv*xv + (1.f-mv)*xhv;
        out[OUT_XCS + xoff] = xc;
        L.c.xcS[rr][ii] = xc;
        __syncthreads();
        float s = bf[ii];
        const float* wf = Wf + ii*XDv;
        #pragma unroll 4
        for (int k = 0; k < XDv; ++k) s += L.c.xcS[rr][k]*wf[k];
        s -= L.c.xcS[rr][ii]*wf[ii];   // feat_m zeroes the diagonal
        float zc = mv*xv + (1.f-mv)*s;
        out[OUT_ZCS + xoff] = zc;
      }
    }
    gridbar(bar, lgen);

    // ---------- Phase D: gx GEMM + GRU -> h ; next-step score partials + gamma(t+1) ----------
    {
      const int btd = bid >> 4, jt = bid & 15;
      const int r0 = btd*32, c0 = jt*32;
      for (int o = tid; o < 32*256; o += NT) {
        int rr = o >> 8, i = o & 255;
        int b = r0 + rr;
        float vl;
        if (i < XDv) vl = out[OUT_ZCS + (b*Tv + t)*XDv + i];
        else vl = masks[(b*Tv + t)*XDv + (i - XDv)];
        L.d.u.inpS[rr][i] = vl;
      }
      for (int o = tid; o < 32*DDv; o += NT) {
        int rr = o >> 4, s2 = o & 15;
        L.d.u.inpS[rr][256 + s2] = statc[(r0+rr)*DDv + s2];
      }
      __syncthreads();
      {
        const int mi = tid >> 5, nj = tid & 31;
        const int i0 = mi*2, j0 = nj*3;
        int dcol[3]; const float* wp[3];
        #pragma unroll
        for (int c = 0; c < 3; ++c) {
          int cj = j0 + c;
          dcol[c] = (cj >> 5)*Hv + c0 + (cj & 31);
          wp[c] = Wih + dcol[c]*INv;
        }
        float acc[2][3] = {{0.f,0.f,0.f},{0.f,0.f,0.f}};
        for (int k = 0; k < INv; k += 4) {
          float4 a0 = *(const float4*)&L.d.u.inpS[i0][k];
          float4 a1 = *(const float4*)&L.d.u.inpS[i0+1][k];
          #pragma unroll
          for (int c = 0; c < 3; ++c) {
            float4 w = *(const float4*)(wp[c] + k);
            acc[0][c] += a0.x*w.x + a0.y*w.y + a0.z*w.z + a0.w*w.w;
            acc[1][c] += a1.x*w.x + a1.y*w.y + a1.z*w.z + a1.w*w.w;
          }
        }
        #pragma unroll
        for (int r = 0; r < 2; ++r)
          #pragma unroll
          for (int c = 0; c < 3; ++c)
            L.d.gxS[i0+r][j0+c] = acc[r][c] + bih[dcol[c]];
      }
      __syncthreads();
      #pragma unroll
      for (int cc = 0; cc < 2; ++cc) {
        int cell = tid + cc*NT;
        int rr = cell >> 5, jj = cell & 31;
        int b = r0 + rr, j = c0 + jj;
        float xr = L.d.gxS[rr][jj], xz = L.d.gxS[rr][32+jj], xn = L.d.gxS[rr][64+jj];
        const float* ghr = w_gh + b*G3v;
        float hr = ghr[j], hz = ghr[Hv + j], hn = ghr[2*Hv + j];
        float r = sig_f(xr + hr), z = sig_f(xz + hz);
        float n = tanh_f(xn + r*hn);
        float hpv = w_hp[b*Hv + j];
        float hnv = (1.f - z)*n + z*hpv;
        float hf = (t < lens[b]) ? hnv : hpv;
        w_hnew[b*Hv + j] = hf;
        out[OUT_HS + (b*Tv + t)*Hv + j] = hf;
        if (t == Tv-1) out[OUT_HN + b*Hv + j] = hf;
        L.d.hfS[rr][jj] = hf;
      }
      __syncthreads();
      // score partials for next step: ps[jt][b][p] = sum_{k in tile} hf[k]*M[p][c0+k]; p==32 -> Wg0 partial
      for (int o = tid; o < 32*33; o += NT) {
        int rr = o / 33, p = o % 33;
        float s = 0.f;
        if (p < 32) {
          const float* mr = w_M + p*Hv + c0;
          #pragma unroll 8
          for (int k = 0; k < 32; ++k) s += L.d.hfS[rr][k]*mr[k];
        } else {
          const float* wg = Wg + c0;
          #pragma unroll 8
          for (int k = 0; k < 32; ++k) s += L.d.hfS[rr][k]*wg[k];
        }
        w_ps[(jt*Bv + (r0+rr))*34 + p] = s;
      }
      if (t + 1 < Tv) {
        for (int o = tid; o < 1024; o += NT) {
          int rr = o >> 5, x4 = (o & 31)*4;
          *(float4*)&L.d.u.timesS[rr][x4] =
            *(const float4*)(times + ((r0+rr)*Tv + (t+1))*XDv + x4);
        }
      }
      __syncthreads();
      if (t + 1 < Tv) {
        for (int o = tid; o < 1024; o += NT) {
          int rr = o >> 5, jj = o & 31;
          int j = c0 + jj;
          const float* wr = Wd + j*XDv;
          float s = bd[j];
          #pragma unroll 4
          for (int x = 0; x < XDv; ++x) s += L.d.u.timesS[rr][x]*wr[x];
          w_gam[(r0+rr)*Hv + j] = __expf(-fmaxf(s, 0.f));
        }
      }
    }
    gridbar(bar, lgen);
  }
}

extern "C" void kernel_launch(void* const* d_in, const int* in_sizes, int n_in,
                              void* d_out, int out_size, void* d_ws, size_t ws_size,
                              hipStream_t stream) {
  (void)in_sizes; (void)n_in; (void)out_size; (void)ws_size;
  hipMemsetAsync(d_ws, 0, 256, stream);  // barrier counter + generation
  rits_main<<<NB, NT, 0, stream>>>(
      (const float*)d_in[0],  (const int*)d_in[1],   (const float*)d_in[2],
      (const float*)d_in[3],  (const float*)d_in[4], (const float*)d_in[5],
      (const int*)d_in[6],
      (const float*)d_in[7],  (const float*)d_in[8],
      (const float*)d_in[9],  (const float*)d_in[10],
      (const float*)d_in[11], (const float*)d_in[12],
      (const float*)d_in[13], (const float*)d_in[14],
      (const float*)d_in[15], (const float*)d_in[16],
      (const float*)d_in[17], (const float*)d_in[18],
      (const float*)d_in[19], (const float*)d_in[20],
      (const float*)d_in[21], (const float*)d_in[22],
      (const float*)d_in[23], (const float*)d_in[24],
      (float*)d_out, (float*)d_ws);
}